// Round 3
// baseline (241.368 us; speedup 1.0000x reference)
//
#include <hip/hip_runtime.h>

#define DIM 128
#define UNROLL 4

// One output row = 128 floats = 32 float4. A group of 32 consecutive lanes
// handles one row: each lane computes the bin index (redundant across the
// group; the distance load is same-address -> HW broadcast) and stores one
// float4 of the gathered embedding row.
//
// emb_table (64 KB) staged in LDS: store data comes off the lgkmcnt path so
// stores never wait on a vmem gather. dist loads for iteration i+1 are issued
// BEFORE iteration i's stores, so retiring them needs only vmcnt(UNROLL) --
// the stores stay in flight across iterations instead of being drained by a
// vmcnt(0) each loop (vmcnt retires in issue order).
__global__ __launch_bounds__(1024) void DistanceEmbedding_kernel(
    const float* __restrict__ dist,   // [R] distances, R = B*N*N
    const float4* __restrict__ emb4,  // [DIM*DIM/4] embedding table as float4
    const float* __restrict__ bins,   // [DIM] bin centers (monotone increasing)
    float4* __restrict__ out,         // [R*32] output rows, float4-granular
    unsigned total4)                  // R*32  (fits 32-bit for this shape)
{
    __shared__ float s_bins[DIM];
    __shared__ float4 s_emb[DIM * DIM / 4];   // 64 KB -> 2 blocks/CU

    #pragma unroll
    for (int i = 0; i < 4; ++i)
        s_emb[threadIdx.x + i * 1024] = emb4[threadIdx.x + i * 1024];
    if (threadIdx.x < DIM) s_bins[threadIdx.x] = bins[threadIdx.x];
    __syncthreads();

    // bins = linspace(0, 32, 128), spacing 32/127. Closed-form nearest bin
    // round(d*127/32) is within +/-1 of true argmin; refine against the real
    // bins with first-min tie-break (matches jnp.argmin). absmax==0 verified.
    const float inv_step = 127.0f / 32.0f;

    const unsigned nthreads = gridDim.x * blockDim.x;
    const unsigned big_stride = nthreads * UNROLL;
    const unsigned base0 = blockIdx.x * blockDim.x + threadIdx.x;
    const unsigned n_full = total4 / big_stride;   // full iterations, all threads in range

    unsigned t0 = base0;

    if (n_full > 0) {
        float d[UNROLL];
        #pragma unroll
        for (int k = 0; k < UNROLL; ++k)
            d[k] = dist[(t0 + (unsigned)k * nthreads) >> 5];

        for (unsigned it = 0; it < n_full; ++it) {
            float4 v[UNROLL];
            #pragma unroll
            for (int k = 0; k < UNROLL; ++k) {
                const unsigned t = t0 + (unsigned)k * nthreads;
                const int c4 = (int)(t & 31u);
                const float dk = d[k];
                const float x = dk * inv_step;
                int i0 = (int)floorf(x + 0.5f);
                i0 = min(max(i0, 0), DIM - 1);
                const int lo = max(i0 - 1, 0);
                const int hi = min(i0 + 1, DIM - 1);
                int best = lo;
                float bd = fabsf(dk - s_bins[lo]);
                #pragma unroll
                for (int i = 0; i < 2; ++i) {
                    const int cand = lo + 1 + i;
                    if (cand <= hi) {
                        const float cd = fabsf(dk - s_bins[cand]);
                        if (cd < bd) { bd = cd; best = cand; }  // strict <: first-min
                    }
                }
                v[k] = s_emb[best * (DIM / 4) + c4];
            }

            // Prefetch next iteration's distances BEFORE the stores.
            const unsigned t1 = t0 + big_stride;
            if (it + 1 < n_full) {
                #pragma unroll
                for (int k = 0; k < UNROLL; ++k)
                    d[k] = dist[(t1 + (unsigned)k * nthreads) >> 5];
            }

            #pragma unroll
            for (int k = 0; k < UNROLL; ++k)
                out[t0 + (unsigned)k * nthreads] = v[k];

            t0 = t1;
        }
    }

    // Tail (not taken for the bench shape; kept for generality).
    for (; t0 < total4; t0 += nthreads) {
        const float dk = dist[t0 >> 5];
        const int c4 = (int)(t0 & 31u);
        const float x = dk * inv_step;
        int i0 = (int)floorf(x + 0.5f);
        i0 = min(max(i0, 0), DIM - 1);
        const int lo = max(i0 - 1, 0);
        const int hi = min(i0 + 1, DIM - 1);
        int best = lo;
        float bd = fabsf(dk - s_bins[lo]);
        for (int cand = lo + 1; cand <= hi; ++cand) {
            const float cd = fabsf(dk - s_bins[cand]);
            if (cd < bd) { bd = cd; best = cand; }
        }
        out[t0] = s_emb[best * (DIM / 4) + c4];
    }
}

extern "C" void kernel_launch(void* const* d_in, const int* in_sizes, int n_in,
                              void* d_out, int out_size, void* d_ws, size_t ws_size,
                              hipStream_t stream) {
    const float* dist = (const float*)d_in[0];    // [2,1024,1024] f32
    const float4* emb = (const float4*)d_in[1];   // [128,128] f32
    const float* bins = (const float*)d_in[2];    // [128] f32
    float4* out = (float4*)d_out;                 // [2,1024,1024,128] f32

    const unsigned R = (unsigned)in_sizes[0];     // number of distance elements
    const unsigned total4 = R * (DIM / 4);        // float4 units in output

    const int block = 1024;                       // 2 blocks/CU (64KB LDS), 8 waves/SIMD
    const int grid = 512;
    DistanceEmbedding_kernel<<<grid, block, 0, stream>>>(
        dist, emb, bins, out, total4);
}

// Round 4
// 213.159 us; speedup vs baseline: 1.1323x; 1.1323x over previous
//
#include <hip/hip_runtime.h>

#define DIM 128
#define UNROLL 8
#define BLOCK 256
#define CHUNK (BLOCK * UNROLL)   // float4 units per block = 2048

// One-shot grid: each 256-thread block handles one contiguous 32 KB chunk of
// the output (2048 float4). 32768 blocks -> ~128 blocks/CU over the kernel's
// lifetime, so CU load imbalance amortizes away (vs 2 persistent blocks/CU
// before). Each thread: 8 dist loads -> 8 emb gathers -> 8 stores, no loop,
// so nothing ever forces a vmcnt(0) drain of outstanding stores.
//
// Within a 32-lane group all lanes share one distance (broadcast load) and
// gather one contiguous 512 B emb row (perfectly coalesced, L1/L2-resident:
// the table is only 64 KB). Bins stay in LDS (512 B) so the bin refine is on
// the lgkm path, keeping the vmem queue for gathers+stores only.
__global__ __launch_bounds__(BLOCK, 8) void DistanceEmbedding_kernel(
    const float* __restrict__ dist,   // [R] distances
    const float4* __restrict__ emb4,  // [DIM*DIM/4] table as float4
    const float* __restrict__ bins,   // [DIM] bin centers (monotone)
    float4* __restrict__ out,         // [R*32] output
    unsigned total4)                  // R*32
{
    __shared__ float s_bins[DIM];
    if (threadIdx.x < DIM) s_bins[threadIdx.x] = bins[threadIdx.x];
    __syncthreads();

    // bins = linspace(0, 32, 128), spacing 32/127. Closed-form nearest bin
    // round(d*127/32) is within +/-1 of true argmin; refine against the real
    // bins with first-min tie-break (matches jnp.argmin). absmax==0 verified.
    const float inv_step = 127.0f / 32.0f;

    const unsigned base = blockIdx.x * (unsigned)CHUNK + threadIdx.x;

    float d[UNROLL];
    #pragma unroll
    for (int k = 0; k < UNROLL; ++k) {
        const unsigned t = base + (unsigned)k * BLOCK;
        d[k] = dist[min(t, total4 - 1u) >> 5];
    }

    float4 v[UNROLL];
    #pragma unroll
    for (int k = 0; k < UNROLL; ++k) {
        const unsigned t = base + (unsigned)k * BLOCK;
        const float dk = d[k];
        const float x = dk * inv_step;
        int i0 = (int)floorf(x + 0.5f);
        i0 = min(max(i0, 0), DIM - 1);
        const int lo = max(i0 - 1, 0);
        const int hi = min(i0 + 1, DIM - 1);
        int best = lo;
        float bd = fabsf(dk - s_bins[lo]);
        #pragma unroll
        for (int i = 0; i < 2; ++i) {
            const int cand = lo + 1 + i;
            if (cand <= hi) {
                const float cd = fabsf(dk - s_bins[cand]);
                if (cd < bd) { bd = cd; best = cand; }  // strict <: first-min
            }
        }
        v[k] = emb4[best * (DIM / 4) + (int)(t & 31u)];
    }

    #pragma unroll
    for (int k = 0; k < UNROLL; ++k) {
        const unsigned t = base + (unsigned)k * BLOCK;
        if (t < total4) out[t] = v[k];
    }
}

extern "C" void kernel_launch(void* const* d_in, const int* in_sizes, int n_in,
                              void* d_out, int out_size, void* d_ws, size_t ws_size,
                              hipStream_t stream) {
    const float* dist = (const float*)d_in[0];    // [2,1024,1024] f32
    const float4* emb = (const float4*)d_in[1];   // [128,128] f32
    const float* bins = (const float*)d_in[2];    // [128] f32
    float4* out = (float4*)d_out;                 // [2,1024,1024,128] f32

    const unsigned R = (unsigned)in_sizes[0];     // distance elements
    const unsigned total4 = R * (DIM / 4);        // float4 units in output

    const unsigned grid = (total4 + CHUNK - 1) / CHUNK;   // 32768 for bench shape
    DistanceEmbedding_kernel<<<grid, BLOCK, 0, stream>>>(
        dist, emb, bins, out, total4);
}

// Round 6
// 203.386 us; speedup vs baseline: 1.1867x; 1.0481x over previous
//
#include <hip/hip_runtime.h>

#define DIM 128
#define UNROLL 8
#define BLOCK 256
#define CHUNK (BLOCK * UNROLL)   // float4 units per block = 2048

typedef float nfloat4 __attribute__((ext_vector_type(4)));  // native vector:
// __builtin_nontemporal_store requires a clang vector type, not HIP_vector_type.

// One-shot grid: each 256-thread block handles one contiguous 32 KB chunk of
// the output (2048 float4). ~128 blocks/CU over the kernel's lifetime, so CU
// load imbalance amortizes away. Each thread: 8 dist loads -> 8 emb gathers
// -> 8 stores, no loop, so nothing forces a vmcnt(0) drain of pending stores.
//
// Stores are NONTEMPORAL: the 1 GiB write stream would otherwise sweep each
// XCD's 4 MB L2 continuously, evicting the 64 KB emb table and dist lines and
// turning the gathers into ~LLC-latency misses on the store-dependent chain.
// nt stores bypass L2 allocation so the table stays L2-resident.
//
// Within a 32-lane group all lanes share one distance (broadcast load) and
// gather one contiguous 512 B emb row (coalesced, L1/L2-resident). Bins stay
// in LDS (512 B) so the bin refine is on the lgkm path.
__global__ __launch_bounds__(BLOCK, 8) void DistanceEmbedding_kernel(
    const float* __restrict__ dist,    // [R] distances
    const nfloat4* __restrict__ emb4,  // [DIM*DIM/4] table as float4
    const float* __restrict__ bins,    // [DIM] bin centers (monotone)
    nfloat4* __restrict__ out,         // [R*32] output
    unsigned total4)                   // R*32
{
    __shared__ float s_bins[DIM];
    if (threadIdx.x < DIM) s_bins[threadIdx.x] = bins[threadIdx.x];
    __syncthreads();

    // bins = linspace(0, 32, 128), spacing 32/127. Closed-form nearest bin
    // round(d*127/32) is within +/-1 of true argmin; refine against the real
    // bins with first-min tie-break (matches jnp.argmin). absmax==0 verified.
    const float inv_step = 127.0f / 32.0f;

    const unsigned base = blockIdx.x * (unsigned)CHUNK + threadIdx.x;

    float d[UNROLL];
    #pragma unroll
    for (int k = 0; k < UNROLL; ++k) {
        const unsigned t = base + (unsigned)k * BLOCK;
        d[k] = dist[min(t, total4 - 1u) >> 5];
    }

    nfloat4 v[UNROLL];
    #pragma unroll
    for (int k = 0; k < UNROLL; ++k) {
        const unsigned t = base + (unsigned)k * BLOCK;
        const float dk = d[k];
        const float x = dk * inv_step;
        int i0 = (int)floorf(x + 0.5f);
        i0 = min(max(i0, 0), DIM - 1);
        const int lo = max(i0 - 1, 0);
        const int hi = min(i0 + 1, DIM - 1);
        int best = lo;
        float bd = fabsf(dk - s_bins[lo]);
        #pragma unroll
        for (int i = 0; i < 2; ++i) {
            const int cand = lo + 1 + i;
            if (cand <= hi) {
                const float cd = fabsf(dk - s_bins[cand]);
                if (cd < bd) { bd = cd; best = cand; }  // strict <: first-min
            }
        }
        v[k] = emb4[best * (DIM / 4) + (int)(t & 31u)];
    }

    #pragma unroll
    for (int k = 0; k < UNROLL; ++k) {
        const unsigned t = base + (unsigned)k * BLOCK;
        if (t < total4) __builtin_nontemporal_store(v[k], &out[t]);
    }
}

extern "C" void kernel_launch(void* const* d_in, const int* in_sizes, int n_in,
                              void* d_out, int out_size, void* d_ws, size_t ws_size,
                              hipStream_t stream) {
    const float* dist = (const float*)d_in[0];      // [2,1024,1024] f32
    const nfloat4* emb = (const nfloat4*)d_in[1];   // [128,128] f32
    const float* bins = (const float*)d_in[2];      // [128] f32
    nfloat4* out = (nfloat4*)d_out;                 // [2,1024,1024,128] f32

    const unsigned R = (unsigned)in_sizes[0];       // distance elements
    const unsigned total4 = R * (DIM / 4);          // float4 units in output

    const unsigned grid = (total4 + CHUNK - 1) / CHUNK;   // 32768 for bench shape
    DistanceEmbedding_kernel<<<grid, BLOCK, 0, stream>>>(
        dist, emb, bins, out, total4);
}